// Round 11
// baseline (104.563 us; speedup 1.0000x reference)
//
#include <hip/hip_runtime.h>

#define NS 65536
#define DD 32
#define RR 128
#define SPB 32            // samples per block
#define STR 132           // padded LDS row stride (floats)
#define NBLK (NS / SPB)   // 2048 blocks

typedef float f2 __attribute__((ext_vector_type(2)));

static __device__ __forceinline__ f2 pkfma(f2 a, f2 b, f2 c) {
    f2 d;
    asm("v_pk_fma_f32 %0, %1, %2, %3" : "=v"(d) : "v"(a), "v"(b), "v"(c));
    return d;
}
static __device__ __forceinline__ f2 pkadd(f2 a, f2 b) {
    f2 d;
    asm("v_pk_add_f32 %0, %1, %2" : "=v"(d) : "v"(a), "v"(b));
    return d;
}
// intra-quad lane swaps via DPP (VALU pipe, no LDS, no barrier)
static __device__ __forceinline__ float dpp_x1(float x) {  // lane ^= 1
    return __int_as_float(__builtin_amdgcn_update_dpp(
        0, __float_as_int(x), 0xB1 /*quad_perm(1,0,3,2)*/, 0xF, 0xF, true));
}
static __device__ __forceinline__ float dpp_x2(float x) {  // lane ^= 2
    return __int_as_float(__builtin_amdgcn_update_dpp(
        0, __float_as_int(x), 0x4E /*quad_perm(2,3,0,1)*/, 0xF, 0xF, true));
}

// R15: quarter-split. thread = (rule, dim-quarter); 512-thr blocks.
// R14 (half-split, ~105 regs, 4 waves/SIMD) moved dur 45.5 -> ~40us — the first
// fix that moved the wall, confirming the unified-VGPR/residency model. R15
// pulls the same lever further: params/thread = 25 regs, total demand ~60-70,
// (512,6) -> ~85-reg budget (anti-R8 margin), 6 waves/SIMD = 24 waves/CU =
// 1.5x R14 residency. Quad reduction = 2 DPP butterfly steps (0xB1, 0x4E) on a
// packed (s,r) f2 with v_pk_add — no LDS, no barrier, partners in-quad.
// Issue grows ~1.5x but 8 rounds of evidence say dur is stall-dominated;
// trading issue for TLP is the direction every data point supports.
__global__ __launch_bounds__(512, 6) void anfis_main(
    const float* __restrict__ X, const float* __restrict__ A,
    const float* __restrict__ B, const float* __restrict__ C,
    float* __restrict__ out_pred, float* __restrict__ out_str,
    float* __restrict__ out_norm)
{
    __shared__ float SBUF[SPB * STR];   // strengths, row = sample-in-block
    __shared__ float PBUF[SPB * STR];   // strength * rule_out
    __shared__ float XT[SPB * DD];      // block's X tile (4KB)
    __shared__ float pS[SPB][8];
    __shared__ float pD[SPB][8];
    __shared__ float scale_lds[SPB];

    const int tid   = threadIdx.x;
    const int rule  = tid >> 2;         // 0..127
    const int q     = tid & 3;          // dim-quarter: dims q*8 .. q*8+7
    const int nbase = blockIdx.x * SPB;

    // ---- stage X tile to LDS (4KB, 1 float4 for first 256 threads) ----
    if (tid < 256)
        ((float4*)XT)[tid] = ((const float4*)(X + (size_t)nbase * DD))[tid];

    // ---- per-thread QUARTER-rule params (24 + 1 regs); A/B reads are
    //      perfectly coalesced: byte offset = tid * 32 ----
    f2 w_[4], n_[4], c_[4];
    float biasv;
    {
        const float4* av = (const float4*)(A + rule * DD + q * 8);
        const float4* bv = (const float4*)(B + rule * DD + q * 8);
        const float*  cp = C + rule * (DD + 1) + q * 8;
        #pragma unroll
        for (int i = 0; i < 2; ++i) {
            float4 va = av[i], vb = bv[i];
            float w0 = 0.8493218003f * __builtin_amdgcn_rcpf(fmaxf(vb.x, 1e-8f));
            float w1 = 0.8493218003f * __builtin_amdgcn_rcpf(fmaxf(vb.y, 1e-8f));
            float w2 = 0.8493218003f * __builtin_amdgcn_rcpf(fmaxf(vb.z, 1e-8f));
            float w3 = 0.8493218003f * __builtin_amdgcn_rcpf(fmaxf(vb.w, 1e-8f));
            w_[2*i+0] = f2{w0, w1};          w_[2*i+1] = f2{w2, w3};
            n_[2*i+0] = f2{-va.x * w0, -va.y * w1};
            n_[2*i+1] = f2{-va.z * w2, -va.w * w3};
            c_[2*i+0] = f2{cp[4*i + 0], cp[4*i + 1]};
            c_[2*i+1] = f2{cp[4*i + 2], cp[4*i + 3]};
        }
        biasv = (q == 3) ? C[rule * (DD + 1) + DD] : 0.0f;  // bias in quarter 3
    }
    __syncthreads();                    // XT visible to all 8 waves

    // Pin params: forbid rematerialization/reload inside the sample loop.
    #pragma unroll
    for (int i = 0; i < 4; ++i)
        asm("" : "+v"(w_[i]), "+v"(n_[i]), "+v"(c_[i]));
    asm("" : "+v"(biasv));

    // parity-selected row buffer: q==0 lanes write strengths, q==1 lanes write
    // strength*rule_out; q>=2 lanes write nothing.
    float* wbuf = (q & 1) ? PBUF : SBUF;

    // this thread's 8 dims of sample jj: 2 ds_read_b128, 4 distinct addresses
    // per wave (16-way same-address broadcast each -> conflict-free).
    #define LOADQ(buf, jj) { \
        buf[0] = *(const float4*)&XT[(jj) * DD + q * 8]; \
        buf[1] = *(const float4*)&XT[(jj) * DD + q * 8 + 4]; }

    // one sample: 12 pk_fma + packed quad-butterfly (4 dpp + 2 pk_add) + exp
    #define DOSAMPLE(buf, jj) { \
        f2 s = f2{0.f, 0.f}, r = f2{biasv, 0.f}; \
        const f2* xp = (const f2*)buf; \
        _Pragma("unroll") \
        for (int g = 0; g < 4; ++g) { \
            f2 t = pkfma(xp[g], w_[g], n_[g]); \
            s = pkfma(t, t, s); \
            r = pkfma(xp[g], c_[g], r); \
        } \
        f2 v = f2{s.x + s.y, r.x + r.y}; \
        v = pkadd(v, f2{dpp_x1(v.x), dpp_x1(v.y)}); \
        v = pkadd(v, f2{dpp_x2(v.x), dpp_x2(v.y)}); \
        float st = __builtin_amdgcn_exp2f(-v.x); \
        if (q < 2) wbuf[(jj) * STR + rule] = q ? st * v.y : st; }

    float4 qa[2], qb[2];
    LOADQ(qa, 0)
    for (int j = 0; j < SPB; j += 2) {
        LOADQ(qb, j + 1)                    // prefetch j+1 while computing j
        DOSAMPLE(qa, j)
        if (j + 2 < SPB) LOADQ(qa, j + 2)   // prefetch j+2 while computing j+1
        DOSAMPLE(qb, j + 1)
    }
    #undef LOADQ
    #undef DOSAMPLE
    __syncthreads();

    // ---- per-sample sums over rules: 32 samples x 8 octants = 256 slots ----
    if (tid < 256) {
        int s = tid >> 3, o = tid & 7;      // 16B-group o covers 16 floats
        const float4* srow = (const float4*)&SBUF[s * STR + o * 16];
        const float4* prow = (const float4*)&PBUF[s * STR + o * 16];
        float ss = 0.f, dd = 0.f;
        #pragma unroll
        for (int k = 0; k < 4; ++k) {
            float4 v = srow[k]; ss += (v.x + v.y) + (v.z + v.w);
            float4 p = prow[k]; dd += (p.x + p.y) + (p.z + p.w);
        }
        pS[s][o] = ss; pD[s][o] = dd;
    }
    __syncthreads();
    float predv = 0.f;
    if (tid < SPB) {
        float ss = 0.f, dd = 0.f;
        #pragma unroll
        for (int o = 0; o < 8; ++o) { ss += pS[tid][o]; dd += pD[tid][o]; }
        float sc = 1.0f / (ss + 1e-8f);
        predv = dd * sc;                // store deferred past the barrier
        scale_lds[tid] = sc;
    }
    __syncthreads();
    if (tid < SPB) out_pred[nbase + tid] = predv;

    // ---- flush strengths + normalized, float4-coalesced (32x32 float4) ----
    #pragma unroll
    for (int it = 0; it < 2; ++it) {
        int f   = it * 512 + tid;       // float4 index over 32x32 tile
        int row = f >> 5;
        int col = f & 31;
        float4 v = *(const float4*)&SBUF[row * STR + col * 4];
        float sc = scale_lds[row];
        size_t base = ((size_t)(nbase + row)) * RR + col * 4;
        *(float4*)(out_str  + base) = v;
        *(float4*)(out_norm + base) = make_float4(v.x * sc, v.y * sc, v.z * sc, v.w * sc);
    }
}

extern "C" void kernel_launch(void* const* d_in, const int* in_sizes, int n_in,
                              void* d_out, int out_size, void* d_ws, size_t ws_size,
                              hipStream_t stream) {
    const float* X = (const float*)d_in[0];
    const float* A = (const float*)d_in[1];
    const float* B = (const float*)d_in[2];
    const float* C = (const float*)d_in[3];

    float* pred = (float*)d_out;
    float* str  = pred + NS;
    float* nrm  = str + (size_t)NS * RR;

    anfis_main<<<dim3(NBLK), dim3(512), 0, stream>>>(X, A, B, C, pred, str, nrm);
}

// Round 12
// 100.062 us; speedup vs baseline: 1.0450x; 1.0450x over previous
//
#include <hip/hip_runtime.h>

#define NS 65536
#define DD 32
#define RR 128
#define SPB 16            // samples per block (R16: back to 16 to cut LDS/block)
#define STR 132           // padded LDS row stride (floats)
#define NBLK (NS / SPB)   // 4096 blocks

typedef float f2 __attribute__((ext_vector_type(2)));

static __device__ __forceinline__ f2 pkfma(f2 a, f2 b, f2 c) {
    f2 d;
    asm("v_pk_fma_f32 %0, %1, %2, %3" : "=v"(d) : "v"(a), "v"(b), "v"(c));
    return d;
}

// neighbor-lane (xor 1) value via DPP quad_perm [1,0,3,2] — VALU pipe only.
static __device__ __forceinline__ float dpp_x1(float x) {
    return __int_as_float(__builtin_amdgcn_update_dpp(
        0, __float_as_int(x), 0xB1 /*quad_perm(1,0,3,2)*/, 0xF, 0xF, true));
}

// R16 = R14 exactly (half-split lane pairs, proven best: kernel ~40us) with
// SPB 32->16 and __launch_bounds__(256,5).
// Why: R15 (quarter-split) showed +residency with +tail-issue LOSES at >=4
// waves/SIMD — issue matters again there. R14's occupancy is LDS-capped, not
// reg-capped: demand ~90 regs would allow 5 waves/SIMD (512/90), but 40KB LDS
// (SPB=32) allows only 4 blocks x 4 waves = 16 waves/CU. SPB=16 cuts LDS to
// ~20.5KB (7 blocks LDS-wise) so the register file binds instead: 5 blocks x
// 4 waves = 20 waves/CU (+25% residency) at an IDENTICAL per-thread stream.
// (256,5): budget 102 >= ~90 demand -> no R8-style spill, 5th wave allowed.
// Per-(sample,rule) arithmetic and reduction orders identical to R14 =>
// absmax back to exactly 8.077936e-28.
__global__ __launch_bounds__(256, 5) void anfis_main(
    const float* __restrict__ X, const float* __restrict__ A,
    const float* __restrict__ B, const float* __restrict__ C,
    float* __restrict__ out_pred, float* __restrict__ out_str,
    float* __restrict__ out_norm)
{
    __shared__ float SBUF[SPB * STR];   // strengths, row = sample-in-block
    __shared__ float PBUF[SPB * STR];   // strength * rule_out
    __shared__ float XT[SPB * DD];      // block's X tile (2KB)
    __shared__ float pS[SPB][8];
    __shared__ float pD[SPB][8];
    __shared__ float scale_lds[SPB];

    const int tid   = threadIdx.x;
    const int rule  = tid >> 1;         // 0..127
    const int half  = tid & 1;          // dim-half: 0 -> dims 0-15, 1 -> 16-31
    const int xoff  = half * 16;
    const int nbase = blockIdx.x * SPB;

    // ---- stage X tile to LDS (2KB, 1 float4 for first 128 threads) ----
    if (tid < 128)
        ((float4*)XT)[tid] = ((const float4*)(X + (size_t)nbase * DD))[tid];

    // ---- per-thread HALF-rule params -> VGPR pairs (48 + 1 regs) ----
    f2 w01_[4], w23_[4], n01_[4], n23_[4], c01_[4], c23_[4];
    float biasv;
    {
        const float4* av = (const float4*)(A + rule * DD + xoff);
        const float4* bv = (const float4*)(B + rule * DD + xoff);
        const float*  cp = C + rule * (DD + 1) + xoff;
        #pragma unroll
        for (int i = 0; i < 4; ++i) {
            float4 va = av[i], vb = bv[i];
            float w0 = 0.8493218003f * __builtin_amdgcn_rcpf(fmaxf(vb.x, 1e-8f));
            float w1 = 0.8493218003f * __builtin_amdgcn_rcpf(fmaxf(vb.y, 1e-8f));
            float w2 = 0.8493218003f * __builtin_amdgcn_rcpf(fmaxf(vb.z, 1e-8f));
            float w3 = 0.8493218003f * __builtin_amdgcn_rcpf(fmaxf(vb.w, 1e-8f));
            w01_[i] = f2{w0, w1};            w23_[i] = f2{w2, w3};
            n01_[i] = f2{-va.x * w0, -va.y * w1};
            n23_[i] = f2{-va.z * w2, -va.w * w3};
            c01_[i] = f2{cp[4*i + 0], cp[4*i + 1]};
            c23_[i] = f2{cp[4*i + 2], cp[4*i + 3]};
        }
        biasv = half ? C[rule * (DD + 1) + DD] : 0.0f;  // bias lives in half 1
    }
    __syncthreads();                    // XT visible to all 4 waves

    // Pin params: forbid rematerialization/reload inside the sample loop.
    #pragma unroll
    for (int i = 0; i < 4; ++i)
        asm("" : "+v"(w01_[i]), "+v"(w23_[i]), "+v"(n01_[i]),
                 "+v"(n23_[i]), "+v"(c01_[i]), "+v"(c23_[i]));
    asm("" : "+v"(biasv));

    // parity-selected output row buffer: even lanes write strengths,
    // odd lanes write strength*rule_out — one non-divergent ds_write each.
    float* wbuf = half ? PBUF : SBUF;

    // 16 dims of sample jj for this half: 4 ds_read_b128, 2 distinct
    // addresses per wave (32-way same-address broadcast = conflict-free).
    #define LOADQ(buf, jj) { _Pragma("unroll") \
        for (int g = 0; g < 4; ++g) \
            buf[g] = *(const float4*)&XT[(jj) * DD + xoff + g * 4]; }

    // one sample: 12 pk_fma + 2 dpp-reduces + exp2 + 1 LDS write
    #define DOSAMPLE(buf, jj) { \
        f2 s01 = f2{0.f, 0.f}, s23 = f2{0.f, 0.f}; \
        f2 r01 = f2{biasv, 0.f}, r23 = f2{0.f, 0.f}; \
        _Pragma("unroll") \
        for (int g = 0; g < 4; ++g) { \
            const f2* xp2 = (const f2*)&buf[g]; \
            f2 x01 = xp2[0], x23 = xp2[1]; \
            f2 t01 = pkfma(x01, w01_[g], n01_[g]); \
            s01 = pkfma(t01, t01, s01); \
            r01 = pkfma(x01, c01_[g], r01); \
            f2 t23 = pkfma(x23, w23_[g], n23_[g]); \
            s23 = pkfma(t23, t23, s23); \
            r23 = pkfma(x23, c23_[g], r23); \
        } \
        float sh = (s01.x + s01.y) + (s23.x + s23.y); \
        float rh = (r01.x + r01.y) + (r23.x + r23.y); \
        float stot = sh + dpp_x1(sh); \
        float rtot = rh + dpp_x1(rh); \
        float st = __builtin_amdgcn_exp2f(-stot); \
        wbuf[(jj) * STR + rule] = half ? st * rtot : st; }

    float4 qa[4], qb[4];
    LOADQ(qa, 0)
    for (int j = 0; j < SPB; j += 2) {
        LOADQ(qb, j + 1)                    // prefetch j+1 while computing j
        DOSAMPLE(qa, j)
        if (j + 2 < SPB) LOADQ(qa, j + 2)   // prefetch j+2 while computing j+1
        DOSAMPLE(qb, j + 1)
    }
    #undef LOADQ
    #undef DOSAMPLE
    __syncthreads();

    // ---- per-sample sums over rules: 16 samples x 8 octants = 128 threads ----
    if (tid < 128) {
        int s = tid >> 3, o = tid & 7;      // 16B-group o covers 16 floats
        const float4* srow = (const float4*)&SBUF[s * STR + o * 16];
        const float4* prow = (const float4*)&PBUF[s * STR + o * 16];
        float ss = 0.f, dd = 0.f;
        #pragma unroll
        for (int k = 0; k < 4; ++k) {
            float4 v = srow[k]; ss += (v.x + v.y) + (v.z + v.w);
            float4 p = prow[k]; dd += (p.x + p.y) + (p.z + p.w);
        }
        pS[s][o] = ss; pD[s][o] = dd;
    }
    __syncthreads();
    float predv = 0.f;
    if (tid < SPB) {
        float ss = 0.f, dd = 0.f;
        #pragma unroll
        for (int o = 0; o < 8; ++o) { ss += pS[tid][o]; dd += pD[tid][o]; }
        float sc = 1.0f / (ss + 1e-8f);
        predv = dd * sc;                // store deferred past the barrier
        scale_lds[tid] = sc;
    }
    __syncthreads();
    if (tid < SPB) out_pred[nbase + tid] = predv;

    // ---- flush strengths + normalized, float4-coalesced (16x32 float4) ----
    #pragma unroll
    for (int it = 0; it < 2; ++it) {
        int f   = it * 256 + tid;       // float4 index over 16x32 tile
        int row = f >> 5;
        int col = f & 31;
        float4 v = *(const float4*)&SBUF[row * STR + col * 4];
        float sc = scale_lds[row];
        size_t base = ((size_t)(nbase + row)) * RR + col * 4;
        *(float4*)(out_str  + base) = v;
        *(float4*)(out_norm + base) = make_float4(v.x * sc, v.y * sc, v.z * sc, v.w * sc);
    }
}

extern "C" void kernel_launch(void* const* d_in, const int* in_sizes, int n_in,
                              void* d_out, int out_size, void* d_ws, size_t ws_size,
                              hipStream_t stream) {
    const float* X = (const float*)d_in[0];
    const float* A = (const float*)d_in[1];
    const float* B = (const float*)d_in[2];
    const float* C = (const float*)d_in[3];

    float* pred = (float*)d_out;
    float* str  = pred + NS;
    float* nrm  = str + (size_t)NS * RR;

    anfis_main<<<dim3(NBLK), dim3(256), 0, stream>>>(X, A, B, C, pred, str, nrm);
}